// Round 10
// baseline (93.119 us; speedup 1.0000x reference)
//
#include <hip/hip_runtime.h>

#pragma clang fp contract(off)

#define N_PTS   16384
#define N_SEEDS 20
#define KP1     11      // K+1, K=10
#define NBIN    512     // bits(d2) >> 22
#define NREP    32      // hist[bin*32 + (t&31)] -> bank == t&31 (conflict-free)
#define CAP     4096    // candidate buffer; also LDS pad: >80KB -> 1 block/CU

typedef unsigned long long u64;
typedef unsigned int       u32;

__device__ __forceinline__ u64 shfl_xor_u64(u64 v, int off) {
    int lo = __shfl_xor((int)(u32)(v & 0xffffffffull), off);
    int hi = __shfl_xor((int)(u32)(v >> 32), off);
    return ((u64)(u32)hi << 32) | (u32)lo;
}

#define FDECL(i) float px##i, py##i, pz##i, dd##i = 1e10f;
#define LOADPTS(P4)                                                         \
    {   const int f4 = t * 12;                                              \
        const float4 q0 = P4[f4+0],  q1 = P4[f4+1],  q2  = P4[f4+2];        \
        const float4 q3 = P4[f4+3],  q4 = P4[f4+4],  q5  = P4[f4+5];        \
        const float4 q6 = P4[f4+6],  q7 = P4[f4+7],  q8  = P4[f4+8];        \
        const float4 q9 = P4[f4+9],  q10 = P4[f4+10], q11 = P4[f4+11];      \
        px0 =q0.x;  py0 =q0.y;  pz0 =q0.z;                                  \
        px1 =q0.w;  py1 =q1.x;  pz1 =q1.y;                                  \
        px2 =q1.z;  py2 =q1.w;  pz2 =q2.x;                                  \
        px3 =q2.y;  py3 =q2.z;  pz3 =q2.w;                                  \
        px4 =q3.x;  py4 =q3.y;  pz4 =q3.z;                                  \
        px5 =q3.w;  py5 =q4.x;  pz5 =q4.y;                                  \
        px6 =q4.z;  py6 =q4.w;  pz6 =q5.x;                                  \
        px7 =q5.y;  py7 =q5.z;  pz7 =q5.w;                                  \
        px8 =q6.x;  py8 =q6.y;  pz8 =q6.z;                                  \
        px9 =q6.w;  py9 =q7.x;  pz9 =q7.y;                                  \
        px10=q7.z;  py10=q7.w;  pz10=q8.x;                                  \
        px11=q8.y;  py11=q8.z;  pz11=q8.w;                                  \
        px12=q9.x;  py12=q9.y;  pz12=q9.z;                                  \
        px13=q9.w;  py13=q10.x; pz13=q10.y;                                 \
        px14=q10.z; py14=q10.w; pz14=q11.x;                                 \
        px15=q11.y; py15=q11.z; pz15=q11.w; }

// ---------------------------------------------------------------------------
// Single kernel, two sequential phases, 256 blocks x 1024 thr, ~84KB LDS ->
// exactly 1 block/CU on 256 CUs (co-residency guaranteed for all spins).
//
// Phase 1 (FPS, 4-way split): block bid handles quarter sub=bid>>6 of batch
// b1=bid&63 (so a batch's 4 blocks are bids b1+{0,64,128,192}: all ≡ b1 mod 8
// -> same XCD -> L2-local key exchange). Per iteration: local argmax over
// 4096 pts -> block key (dist_bits<<32 | ~gidx, exact first-index semantics)
// -> publish to per-iteration gkey slot (relaxed u64) -> poll 3 partners ->
// global max -> centroid via uniform s_load. Iteration 19's compute is
// skipped (its argmax is discarded by the reference scan).
//
// Phase 2 (kNN select): block bid handles batch b2=(bid&7)+8*(bid>>5)
// (≡ bid mod 8: XCD-local), seeds [g*5, g*5+5) with g=(bid>>3)&3. Points
// loaded once into regs; per seed: poll seeds[] (relaxed), float-bit radix
// histogram (bank-replicated), threshold scan, reg collect, 1-wave rank
// select. Then threadfence + done-add; block 0 waits for 255 and runs stats.
// ---------------------------------------------------------------------------
__global__ __launch_bounds__(1024) void fused_kernel(const float* __restrict__ pcs,
                                                     int* __restrict__ seeds,
                                                     int* __restrict__ done,
                                                     u64* __restrict__ gkey,
                                                     float* __restrict__ topd,
                                                     float* __restrict__ out,
                                                     int B) {
    __shared__ alignas(16) u32 hist[NBIN * NREP];   // 64 KB (knn) / f64 scratch (stats)
    __shared__ u32   part[NBIN];
    __shared__ float cand[CAP];                     // 16 KB (LDS pad -> 1 block/CU)
    __shared__ u32   cnt;
    __shared__ u32   s_thr;
    __shared__ int   s_sid;
    __shared__ u64   s_wk[16];
    __shared__ u64   s_gk;

    const int bid  = blockIdx.x;
    const int t    = threadIdx.x;
    const int lane = t & 63;
    const int wid  = t >> 6;

    // ===================== Phase 1: FPS (4-way split) ======================
    {
        const int b1  = bid & 63;
        const int sub = bid >> 6;
        const float* __restrict__ P  = pcs + (size_t)b1 * N_PTS * 3;
        const float4* __restrict__ P4 = (const float4*)P;
        const int gbase = sub * 4096;

        float px0, py0, pz0, dd0 = 1e10f;
        float px1, py1, pz1, dd1 = 1e10f;
        float px2, py2, pz2, dd2 = 1e10f;
        float px3, py3, pz3, dd3 = 1e10f;
        {   // 4 pts * 3 floats = 3 float4, contiguous per thread
            const int f4 = sub * 3072 + t * 3;
            const float4 q0 = P4[f4], q1 = P4[f4+1], q2 = P4[f4+2];
            px0 = q0.x; py0 = q0.y; pz0 = q0.z;
            px1 = q0.w; py1 = q1.x; pz1 = q1.y;
            px2 = q1.z; py2 = q1.w; pz2 = q2.x;
            px3 = q2.y; py3 = q2.z; pz3 = q2.w;
        }

        float cx = P[0], cy = P[1], cz = P[2];
        int farthest = 0;

        for (int it = 0; it < N_SEEDS; ++it) {
            if (sub == 0 && t == 0)
                __hip_atomic_store(&seeds[b1 * N_SEEDS + it], farthest,
                                   __ATOMIC_RELAXED, __HIP_MEMORY_SCOPE_AGENT);
            if (it == N_SEEDS - 1) break;   // last argmax is discarded by scan

            float bestv = -1.0f;
            int   besti = 0;
#define FQ(i) { const float dx = px##i - cx, dy = py##i - cy, dz = pz##i - cz; \
        const float d  = (dx*dx + dy*dy) + dz*dz; \
        const float nd = fminf(dd##i, d); dd##i = nd; \
        if (nd > bestv) { bestv = nd; besti = gbase + t*4 + (i); } }
            FQ(0) FQ(1) FQ(2) FQ(3)

            // wave argmax (float max + ballot, first-index on ties)
            float wmax = bestv;
            for (int off = 32; off; off >>= 1)
                wmax = fmaxf(wmax, __shfl_xor(wmax, off));
            const u64 msk = __ballot(bestv == wmax);
            const int low = __ffsll((unsigned long long)msk) - 1;
            const int wi  = __shfl(besti, low);
            if (lane == 0)
                s_wk[wid] = ((u64)__float_as_uint(wmax) << 32) | (u32)(~(u32)wi);
            __syncthreads();                       // B1: s_wk ready

            // block max over 16 wave keys (all lanes)
            u64 bk = s_wk[lane & 15];
            for (int off = 8; off; off >>= 1) {
                const u64 o = shfl_xor_u64(bk, off);
                if (o > bk) bk = o;
            }

            // cross-block exchange via per-iteration slots (L2-local, relaxed)
            if (t == 0) {
                const int base = it * 256 + b1 * 4;
                __hip_atomic_store(&gkey[base + sub], bk,
                                   __ATOMIC_RELAXED, __HIP_MEMORY_SCOPE_AGENT);
                u64 g = bk;
                for (int o = 1; o < 4; ++o) {
                    u64 v;
                    while ((v = __hip_atomic_load(&gkey[base + ((sub + o) & 3)],
                                   __ATOMIC_RELAXED, __HIP_MEMORY_SCOPE_AGENT)) == 0ull)
                        __builtin_amdgcn_s_sleep(1);
                    if (v > g) g = v;
                }
                s_gk = g;
            }
            __syncthreads();                       // B2: global key ready

            const int widx = (int)(~(u32)s_gk);
            farthest = widx;
            const int fi = __builtin_amdgcn_readfirstlane(widx);
            cx = P[fi*3]; cy = P[fi*3+1]; cz = P[fi*3+2];
        }
    }

    // ===================== Phase 2: kNN radix-select =======================
    {
        const int b2 = (bid & 7) + 8 * (bid >> 5);
        const int sb = ((bid >> 3) & 3) * 5;

        const float* __restrict__ P  = pcs + (size_t)b2 * N_PTS * 3;
        const float4* __restrict__ P4 = (const float4*)P;
        const int rep = t & 31;

        FDECL(0)  FDECL(1)  FDECL(2)  FDECL(3)
        FDECL(4)  FDECL(5)  FDECL(6)  FDECL(7)
        FDECL(8)  FDECL(9)  FDECL(10) FDECL(11)
        FDECL(12) FDECL(13) FDECL(14) FDECL(15)
        LOADPTS(P4)        // dd regs unused -> DCE'd

#pragma unroll
        for (int i = 0; i < (NBIN * NREP) / 1024; ++i) hist[t + i * 1024] = 0u;
        if (t == 0) cnt = 0u;

        for (int s = sb; s < sb + 5; ++s) {
            if (t == 0) {   // RELAXED poll: seed index is the whole payload
                int sv;
                while ((sv = __hip_atomic_load(&seeds[b2 * N_SEEDS + s],
                               __ATOMIC_RELAXED, __HIP_MEMORY_SCOPE_AGENT)) < 0)
                    __builtin_amdgcn_s_sleep(2);
                s_sid = sv;
            }
            __syncthreads();                  // B0: sid ready, hist+cnt zeroed
            const int sid = s_sid;
            const float cx = P[sid*3], cy = P[sid*3+1], cz = P[sid*3+2];

            float d0,d1,d2,d3,d4,d5,d6,d7,d8,d9,d10,d11,d12,d13,d14,d15;
#define HSTEP(i) { const float dx = px##i - cx, dy = py##i - cy, dz = pz##i - cz; \
        d##i = fmaf(dz, dz, fmaf(dy, dy, dx * dx)); \
        atomicAdd(&hist[(__float_as_uint(d##i) >> 22) * NREP + rep], 1u); }
            HSTEP(0)  HSTEP(1)  HSTEP(2)  HSTEP(3)
            HSTEP(4)  HSTEP(5)  HSTEP(6)  HSTEP(7)
            HSTEP(8)  HSTEP(9)  HSTEP(10) HSTEP(11)
            HSTEP(12) HSTEP(13) HSTEP(14) HSTEP(15)
            __syncthreads();                  // B1: hist complete

            if (t < NBIN) {
                u32 ssum = 0;
#pragma unroll
                for (int r = 0; r < NREP; ++r)
                    ssum += hist[t * NREP + ((r + t) & (NREP - 1))];
                part[t] = ssum;
            }
            __syncthreads();                  // B2: part[] ready

            if (wid == 0) {
                u32 s8 = 0;
#pragma unroll
                for (int i = 0; i < 8; ++i)
                    s8 += part[lane * 8 + ((i + lane) & 7)];
                u32 cum = s8;
                for (int off = 1; off < 64; off <<= 1) {
                    const u32 o = __shfl_up(cum, off);
                    if (lane >= off) cum += o;
                }
                const u64 mm = __ballot(cum >= (u32)KP1);
                const int L  = __ffsll((unsigned long long)mm) - 1;
                const u32 below = __shfl(cum - s8, L);
                const u32 bc = (lane < 8) ? part[L * 8 + lane] : 0u;
                u32 ic = bc;
                for (int off = 1; off < 8; off <<= 1) {
                    const u32 o = __shfl_up(ic, off);
                    if (lane >= off) ic += o;
                }
                const u64 mm2 = __ballot(lane < 8 && (below + ic) >= (u32)KP1);
                const int l2  = __ffsll((unsigned long long)mm2) - 1;
                if (lane == 0) s_thr = (u32)(L * 8 + l2 + 1) << 22;
            } else {
                if (t == 64) cnt = 0u;        // reset for this seed's collect
                for (int i = t - 64; i < NBIN * NREP; i += 960) hist[i] = 0u;
            }
            __syncthreads();                  // B3: thr ready, hist zeroed, cnt=0

            const float thrf = __uint_as_float(s_thr);
#define CSTEP(i) if (d##i < thrf) { const u32 sl = atomicAdd(&cnt, 1u); \
                                    if (sl < (u32)CAP) cand[sl] = d##i; }
            CSTEP(0)  CSTEP(1)  CSTEP(2)  CSTEP(3)
            CSTEP(4)  CSTEP(5)  CSTEP(6)  CSTEP(7)
            CSTEP(8)  CSTEP(9)  CSTEP(10) CSTEP(11)
            CSTEP(12) CSTEP(13) CSTEP(14) CSTEP(15)
            __syncthreads();                  // B4: candidates ready

            if (wid == 0) {
                const u32 n = min(cnt, (u32)CAP);
                for (u32 base = 0; base < n; base += 64) {
                    const u32 idx = base + (u32)lane;
                    const float vv = (idx < n) ? cand[idx] : 3.0e38f;
                    u32 r = 0;
                    for (u32 jj = 0; jj < n; ++jj) {
                        const float w = cand[jj];
                        r += (w < vv || (w == vv && jj < idx)) ? 1u : 0u;
                    }
                    if (idx < n && r < (u32)KP1)
                        topd[(b2 * N_SEEDS + s) * KP1 + r] = sqrtf(vv);
                }
            }
        }

        // -------- completion signal (one fence per block, off hot path) ----
        __syncthreads();
        if (t == 0) {
            __threadfence();                  // make topd visible at agent scope
            __hip_atomic_fetch_add(done, 1, __ATOMIC_RELAXED,
                                   __HIP_MEMORY_SCOPE_AGENT);
        }

        // ===================== stats (block 0 only) ========================
        if (bid == 0) {
            const int target = 4 * B - 1;     // done init = -1 (0xFF memset)
            if (t == 0) {
                while (__hip_atomic_load(done, __ATOMIC_RELAXED,
                                         __HIP_MEMORY_SCOPE_AGENT) != target)
                    __builtin_amdgcn_s_sleep(8);
            }
            __syncthreads();
            __threadfence();                  // acquire side before topd reads

            const int pairs = B * N_SEEDS;
            const int total = pairs * KP1;
            double* red = (double*)hist;      // 8 KB scratch, hist is dead

            double s1 = 0.0;
            for (int i = t; i < total; i += 1024)
                if (i % KP1 != 0) s1 += (double)topd[i];
            red[t] = s1;
            __syncthreads();
            for (int off = 512; off; off >>= 1) {
                if (t < off) red[t] += red[t + off];
                __syncthreads();
            }
            const double om = red[0] / (double)(pairs * (KP1 - 1));

            double sm = 0.0, sm2 = 0.0;
            for (int pr = t; pr < pairs; pr += 1024) {
                double acc = 0.0;
                for (int jj = 0; jj < KP1; ++jj) acc += (double)topd[pr * KP1 + jj];
                const double m = acc / (om * (double)KP1);
                sm += m;
                sm2 += m * m;
            }
            __syncthreads();
            red[t] = sm;
            __syncthreads();
            for (int off = 512; off; off >>= 1) {
                if (t < off) red[t] += red[t + off];
                __syncthreads();
            }
            const double Sm = red[0];
            __syncthreads();
            red[t] = sm2;
            __syncthreads();
            for (int off = 512; off; off >>= 1) {
                if (t < off) red[t] += red[t + off];
                __syncthreads();
            }
            if (t == 0) {
                const double var = (red[0] - Sm * Sm / (double)pairs)
                                   / (double)(pairs - 1);
                out[0] = (float)var;
            }
        }
    }
}

// ---------------------------------------------------------------------------
extern "C" void kernel_launch(void* const* d_in, const int* in_sizes, int n_in,
                              void* d_out, int out_size, void* d_ws, size_t ws_size,
                              hipStream_t stream) {
    const float* pcs = (const float*)d_in[0];
    const int B = in_sizes[0] / (N_PTS * 3);   // 64

    int*   seeds = (int*)d_ws;                          // B*20 ints   @ 0
    int*   done  = (int*)((char*)d_ws + 5120);          // 1 int       @ 5120
    u64*   gkey  = (u64*)((char*)d_ws + 8192);          // 20*64*4 u64 @ 8192  (40960 B)
    float* topd  = (float*)((char*)d_ws + 49152);       // B*20*11 f32 @ 49152 (56320 B)
    float* out   = (float*)d_out;

    // every launch: seeds/done -> -1, gkey -> 0 (graph replays don't re-poison)
    (void)hipMemsetAsync(d_ws, 0xFF, 8192, stream);
    (void)hipMemsetAsync((char*)d_ws + 8192, 0x00, 40960, stream);

    fused_kernel<<<B * 4, 1024, 0, stream>>>(pcs, seeds, done, gkey, topd, out, B);
}

// Round 11
// 91.799 us; speedup vs baseline: 1.0144x; 1.0144x over previous
//
#include <hip/hip_runtime.h>

#pragma clang fp contract(off)

#define N_PTS   16384
#define N_SEEDS 20
#define KP1     11      // K+1, K=10
#define NBIN    512     // bits(d2) >> 22 : exponent + 1 mantissa bit
#define NREP    32      // hist[bin*32 + (t&31)] -> bank == t&31 (conflict-free)
#define CAP     4096    // candidate buffer; also LDS pad: >80KB total -> 1 block/CU
#define NKNN    3       // knn-role blocks per batch

typedef unsigned long long u64;
typedef unsigned int       u32;

#define FDECL(i) float px##i, py##i, pz##i, dd##i = 1e10f;
#define LOADPTS(P4)                                                         \
    {   const int f4 = t * 12;                                              \
        const float4 q0 = P4[f4+0],  q1 = P4[f4+1],  q2  = P4[f4+2];        \
        const float4 q3 = P4[f4+3],  q4 = P4[f4+4],  q5  = P4[f4+5];        \
        const float4 q6 = P4[f4+6],  q7 = P4[f4+7],  q8  = P4[f4+8];        \
        const float4 q9 = P4[f4+9],  q10 = P4[f4+10], q11 = P4[f4+11];      \
        px0 =q0.x;  py0 =q0.y;  pz0 =q0.z;                                  \
        px1 =q0.w;  py1 =q1.x;  pz1 =q1.y;                                  \
        px2 =q1.z;  py2 =q1.w;  pz2 =q2.x;                                  \
        px3 =q2.y;  py3 =q2.z;  pz3 =q2.w;                                  \
        px4 =q3.x;  py4 =q3.y;  pz4 =q3.z;                                  \
        px5 =q3.w;  py5 =q4.x;  pz5 =q4.y;                                  \
        px6 =q4.z;  py6 =q4.w;  pz6 =q5.x;                                  \
        px7 =q5.y;  py7 =q5.z;  pz7 =q5.w;                                  \
        px8 =q6.x;  py8 =q6.y;  pz8 =q6.z;                                  \
        px9 =q6.w;  py9 =q7.x;  pz9 =q7.y;                                  \
        px10=q7.z;  py10=q7.w;  pz10=q8.x;                                  \
        px11=q8.y;  py11=q8.z;  pz11=q8.w;                                  \
        px12=q9.x;  py12=q9.y;  pz12=q9.z;                                  \
        px13=q9.w;  py13=q10.x; pz13=q10.y;                                 \
        px14=q10.z; py14=q10.w; pz14=q11.x;                                 \
        px15=q11.y; py15=q11.z; pz15=q11.w; }

// ---------------------------------------------------------------------------
// One kernel, three roles, all concurrent (256 blocks x 1024 thr, ~84KB LDS
// -> exactly 1 block/CU on 256 CUs -> guaranteed co-residency for spins):
//   bid <  B : FPS for batch bid; publishes seeds[] with RELAXED agent stores.
//              FSTEP uses 4 INDEPENDENT argmax chains (consecutive quartets:
//              all chain-c indices < chain-(c+1) indices per thread, so
//              strict-> merges keep exact first-index semantics). Block
//              reduce = float s_val/s_idx + ballot (r5/r6-proven), parity
//              buffered, 1 barrier/iter. Iter 19 compute skipped (argmax
//              discarded by the reference scan).
//   bid >= B : kNN radix-select; j=(bid-B)/B, b=(bid-B)%B, seeds {j, j+3, …},
//              polling seeds with RELAXED loads. threadfence + done-add after.
//   bid == B : polls done==NKNN*B-1 (init -1), fences, stats in-kernel.
// ---------------------------------------------------------------------------
__global__ __launch_bounds__(1024) void fused_kernel(const float* __restrict__ pcs,
                                                     int* __restrict__ seeds,
                                                     int* __restrict__ done,
                                                     float* __restrict__ topd,
                                                     float* __restrict__ out,
                                                     int B) {
    __shared__ alignas(16) u32 hist[NBIN * NREP];   // 64 KB (knn) / f64 scratch (stats)
    __shared__ u32   part[NBIN];
    __shared__ float cand[CAP];                     // 16 KB (also the >80KB pad)
    __shared__ u32   cnt;
    __shared__ u32   s_thr;
    __shared__ int   s_sid;
    __shared__ float s_val[2][16];                  // fps role (parity-buffered)
    __shared__ int   s_idx[2][16];
    __shared__ float s_cx[2][16], s_cy[2][16], s_cz[2][16];

    const int bid  = blockIdx.x;
    const int t    = threadIdx.x;
    const int lane = t & 63;
    const int wid  = t >> 6;

    if (bid < B) {
        // ================= FPS role =================
        const float* __restrict__ P  = pcs + (size_t)bid * N_PTS * 3;
        const float4* __restrict__ P4 = (const float4*)P;

        FDECL(0)  FDECL(1)  FDECL(2)  FDECL(3)
        FDECL(4)  FDECL(5)  FDECL(6)  FDECL(7)
        FDECL(8)  FDECL(9)  FDECL(10) FDECL(11)
        FDECL(12) FDECL(13) FDECL(14) FDECL(15)
        LOADPTS(P4)

        float cx = P[0], cy = P[1], cz = P[2];
        int farthest = 0;

        for (int it = 0; it < N_SEEDS; ++it) {
            if (t == 0)    // RELAXED: value-only payload (r9-proven)
                __hip_atomic_store(&seeds[bid * N_SEEDS + it], farthest,
                                   __ATOMIC_RELAXED, __HIP_MEMORY_SCOPE_AGENT);
            if (it == N_SEEDS - 1) break;   // last argmax discarded by scan

            // ---- 4 independent chains (quartets) -> ILP in the hot loop ---
            float v0 = -1.f, v1 = -1.f, v2 = -1.f, v3 = -1.f;
            int   ia0 = 0, ia1 = 0, ia2 = 0, ia3 = 0;
            float xx0=0.f,yy0=0.f,zz0=0.f, xx1=0.f,yy1=0.f,zz1=0.f;
            float xx2=0.f,yy2=0.f,zz2=0.f, xx3=0.f,yy3=0.f,zz3=0.f;
#define FS(c,i) { const float dx = px##i - cx, dy = py##i - cy, dz = pz##i - cz; \
        const float d  = (dx*dx + dy*dy) + dz*dz; \
        const float nd = fminf(dd##i, d); dd##i = nd; \
        if (nd > v##c) { v##c = nd; ia##c = t*16 + (i); \
                         xx##c = px##i; yy##c = py##i; zz##c = pz##i; } }
            FS(0,0)  FS(0,1)  FS(0,2)  FS(0,3)
            FS(1,4)  FS(1,5)  FS(1,6)  FS(1,7)
            FS(2,8)  FS(2,9)  FS(2,10) FS(2,11)
            FS(3,12) FS(3,13) FS(3,14) FS(3,15)
            // merges: chain-c indices < chain-(c+1) indices per thread, so
            // strict > (keep lower chain on tie) == exact first-index.
            if (v1 > v0) { v0 = v1; ia0 = ia1; xx0 = xx1; yy0 = yy1; zz0 = zz1; }
            if (v3 > v2) { v2 = v3; ia2 = ia3; xx2 = xx3; yy2 = yy3; zz2 = zz3; }
            if (v2 > v0) { v0 = v2; ia0 = ia2; xx0 = xx2; yy0 = yy2; zz0 = zz2; }

            // ---- wave argmax: float max + ballot (first-index on ties) ----
            float wmax = v0;
            for (int off = 32; off; off >>= 1)
                wmax = fmaxf(wmax, __shfl_xor(wmax, off));
            const u64 msk = __ballot(v0 == wmax);
            const int low = __ffsll((unsigned long long)msk) - 1;
            const int wi  = __shfl(ia0, low);
            const float wx = __shfl(xx0, low);
            const float wy = __shfl(yy0, low);
            const float wz = __shfl(zz0, low);

            const int par = it & 1;
            if (lane == 0) {
                s_val[par][wid] = wmax; s_idx[par][wid] = wi;
                s_cx[par][wid] = wx; s_cy[par][wid] = wy; s_cz[par][wid] = wz;
            }
            __syncthreads();            // B1 (only barrier): s_* ready

            // ---- block argmax over 16 wave maxima (all lanes, r5-proven) --
            const float v16 = s_val[par][lane & 15];
            float g = v16;
            for (int off = 1; off < 16; off <<= 1)
                g = fmaxf(g, __shfl_xor(g, off));
            const u64 m2 = __ballot(v16 == g) & 0xFFFFull;
            const int ws = __ffsll((unsigned long long)m2) - 1;
            farthest = s_idx[par][ws];
            cx = s_cx[par][ws]; cy = s_cy[par][ws]; cz = s_cz[par][ws];
        }
    } else {
        // ================= kNN-select role (r9 bitwise-identical) ==========
        const int kk = bid - B;
        const int b  = kk % B;          // bid ≡ b (mod 8): same XCD as fps block
        const int j  = kk / B;

        const float* __restrict__ P  = pcs + (size_t)b * N_PTS * 3;
        const float4* __restrict__ P4 = (const float4*)P;
        const int rep = t & 31;

        FDECL(0)  FDECL(1)  FDECL(2)  FDECL(3)
        FDECL(4)  FDECL(5)  FDECL(6)  FDECL(7)
        FDECL(8)  FDECL(9)  FDECL(10) FDECL(11)
        FDECL(12) FDECL(13) FDECL(14) FDECL(15)
        LOADPTS(P4)        // dd regs unused -> DCE'd

#pragma unroll
        for (int i = 0; i < (NBIN * NREP) / 1024; ++i) hist[t + i * 1024] = 0u;
        if (t == 0) cnt = 0u;

        for (int s = j; s < N_SEEDS; s += NKNN) {
            if (t == 0) {   // RELAXED poll: seed index is the whole payload
                int sv;
                while ((sv = __hip_atomic_load(&seeds[b * N_SEEDS + s],
                               __ATOMIC_RELAXED, __HIP_MEMORY_SCOPE_AGENT)) < 0)
                    __builtin_amdgcn_s_sleep(2);
                s_sid = sv;
            }
            __syncthreads();                  // B0: sid ready, hist+cnt zeroed
            const int sid = s_sid;
            const float cx = P[sid*3], cy = P[sid*3+1], cz = P[sid*3+2];

            float d0,d1,d2,d3,d4,d5,d6,d7,d8,d9,d10,d11,d12,d13,d14,d15;
#define HSTEP(i) { const float dx = px##i - cx, dy = py##i - cy, dz = pz##i - cz; \
        d##i = fmaf(dz, dz, fmaf(dy, dy, dx * dx)); \
        atomicAdd(&hist[(__float_as_uint(d##i) >> 22) * NREP + rep], 1u); }
            HSTEP(0)  HSTEP(1)  HSTEP(2)  HSTEP(3)
            HSTEP(4)  HSTEP(5)  HSTEP(6)  HSTEP(7)
            HSTEP(8)  HSTEP(9)  HSTEP(10) HSTEP(11)
            HSTEP(12) HSTEP(13) HSTEP(14) HSTEP(15)
            __syncthreads();                  // B1: hist complete

            if (t < NBIN) {
                u32 ssum = 0;
#pragma unroll
                for (int r = 0; r < NREP; ++r)
                    ssum += hist[t * NREP + ((r + t) & (NREP - 1))];
                part[t] = ssum;
            }
            __syncthreads();                  // B2: part[] ready

            if (wid == 0) {
                u32 s8 = 0;
#pragma unroll
                for (int i = 0; i < 8; ++i)
                    s8 += part[lane * 8 + ((i + lane) & 7)];
                u32 cum = s8;
                for (int off = 1; off < 64; off <<= 1) {
                    const u32 o = __shfl_up(cum, off);
                    if (lane >= off) cum += o;
                }
                const u64 mm = __ballot(cum >= (u32)KP1);
                const int L  = __ffsll((unsigned long long)mm) - 1;
                const u32 below = __shfl(cum - s8, L);
                const u32 bc = (lane < 8) ? part[L * 8 + lane] : 0u;
                u32 ic = bc;
                for (int off = 1; off < 8; off <<= 1) {
                    const u32 o = __shfl_up(ic, off);
                    if (lane >= off) ic += o;
                }
                const u64 mm2 = __ballot(lane < 8 && (below + ic) >= (u32)KP1);
                const int l2  = __ffsll((unsigned long long)mm2) - 1;
                if (lane == 0) s_thr = (u32)(L * 8 + l2 + 1) << 22;
            } else {
                if (t == 64) cnt = 0u;        // reset for this seed's collect
                for (int i = t - 64; i < NBIN * NREP; i += 960) hist[i] = 0u;
            }
            __syncthreads();                  // B3: thr ready, hist zeroed, cnt=0

            const float thrf = __uint_as_float(s_thr);
#define CSTEP(i) if (d##i < thrf) { const u32 sl = atomicAdd(&cnt, 1u); \
                                    if (sl < (u32)CAP) cand[sl] = d##i; }
            CSTEP(0)  CSTEP(1)  CSTEP(2)  CSTEP(3)
            CSTEP(4)  CSTEP(5)  CSTEP(6)  CSTEP(7)
            CSTEP(8)  CSTEP(9)  CSTEP(10) CSTEP(11)
            CSTEP(12) CSTEP(13) CSTEP(14) CSTEP(15)
            __syncthreads();                  // B4: candidates ready

            if (wid == 0) {
                const u32 n = min(cnt, (u32)CAP);
                for (u32 base = 0; base < n; base += 64) {
                    const u32 idx = base + (u32)lane;
                    const float vv = (idx < n) ? cand[idx] : 3.0e38f;
                    u32 r = 0;
                    for (u32 jj = 0; jj < n; ++jj) {
                        const float w = cand[jj];
                        r += (w < vv || (w == vv && jj < idx)) ? 1u : 0u;
                    }
                    if (idx < n && r < (u32)KP1)
                        topd[(b * N_SEEDS + s) * KP1 + r] = sqrtf(vv);
                }
            }
        }

        // -------- signal completion (one fence per block, off hot path) ----
        __syncthreads();
        if (t == 0) {
            __threadfence();                  // make topd visible at agent scope
            __hip_atomic_fetch_add(done, 1, __ATOMIC_RELAXED,
                                   __HIP_MEMORY_SCOPE_AGENT);
        }

        // ================= stats role (block B only) =======================
        if (bid == B) {
            const int target = NKNN * B - 1;      // done init = -1 (0xFF memset)
            if (t == 0) {
                while (__hip_atomic_load(done, __ATOMIC_RELAXED,
                                         __HIP_MEMORY_SCOPE_AGENT) != target)
                    __builtin_amdgcn_s_sleep(8);
            }
            __syncthreads();
            __threadfence();    // acquire side: invalidate before topd reads

            const int pairs = B * N_SEEDS;
            const int total = pairs * KP1;
            double* red = (double*)hist;          // 8 KB scratch, hist is dead

            double s1 = 0.0;
            for (int i = t; i < total; i += 1024)
                if (i % KP1 != 0) s1 += (double)topd[i];
            red[t] = s1;
            __syncthreads();
            for (int off = 512; off; off >>= 1) {
                if (t < off) red[t] += red[t + off];
                __syncthreads();
            }
            const double om = red[0] / (double)(pairs * (KP1 - 1));

            double sm = 0.0, sm2 = 0.0;
            for (int pr = t; pr < pairs; pr += 1024) {
                double acc = 0.0;
                for (int jj = 0; jj < KP1; ++jj) acc += (double)topd[pr * KP1 + jj];
                const double m = acc / (om * (double)KP1);
                sm += m;
                sm2 += m * m;
            }
            __syncthreads();
            red[t] = sm;
            __syncthreads();
            for (int off = 512; off; off >>= 1) {
                if (t < off) red[t] += red[t + off];
                __syncthreads();
            }
            const double Sm = red[0];
            __syncthreads();
            red[t] = sm2;
            __syncthreads();
            for (int off = 512; off; off >>= 1) {
                if (t < off) red[t] += red[t + off];
                __syncthreads();
            }
            if (t == 0) {
                const double var = (red[0] - Sm * Sm / (double)pairs)
                                   / (double)(pairs - 1);
                out[0] = (float)var;
            }
        }
    }
}

// ---------------------------------------------------------------------------
extern "C" void kernel_launch(void* const* d_in, const int* in_sizes, int n_in,
                              void* d_out, int out_size, void* d_ws, size_t ws_size,
                              hipStream_t stream) {
    const float* pcs = (const float*)d_in[0];
    const int B = in_sizes[0] / (N_PTS * 3);

    int*   seeds = (int*)d_ws;                          // B*20 ints
    int*   done  = (int*)((char*)d_ws + 5120);          // 1 int, init -1
    float* topd  = (float*)((char*)d_ws + 8192);        // B*20*11 floats
    float* out   = (float*)d_out;

    // seeds -> -1, done -> -1 every launch (graph replays don't re-poison)
    (void)hipMemsetAsync(d_ws, 0xFF, 8192, stream);

    fused_kernel<<<B * (1 + NKNN), 1024, 0, stream>>>(pcs, seeds, done, topd, out, B);
}

// Round 12
// 68.330 us; speedup vs baseline: 1.3628x; 1.3435x over previous
//
#include <hip/hip_runtime.h>

#pragma clang fp contract(off)

#define N_PTS   16384
#define N_SEEDS 20
#define KP1     11      // K+1, K=10
#define NBIN    512     // bits(d2) >> 22 : exponent + 1 mantissa bit
#define NREP    32      // hist[bin*32 + (t&31)] -> bank == t&31 (conflict-free)
#define CAP     4096    // candidate buffer; also LDS pad: >80KB total -> 1 block/CU
#define NKNN    3       // knn-role blocks per batch

typedef unsigned long long u64;
typedef unsigned int       u32;

__device__ __forceinline__ u64 shfl_xor_u64(u64 v, int off) {
    int lo = __shfl_xor((int)(u32)(v & 0xffffffffull), off);
    int hi = __shfl_xor((int)(u32)(v >> 32), off);
    return ((u64)(u32)hi << 32) | (u32)lo;
}

#define FDECL(i) float px##i, py##i, pz##i, dd##i = 1e10f;
#define LOADPTS(P4)                                                         \
    {   const int f4 = t * 12;                                              \
        const float4 q0 = P4[f4+0],  q1 = P4[f4+1],  q2  = P4[f4+2];        \
        const float4 q3 = P4[f4+3],  q4 = P4[f4+4],  q5  = P4[f4+5];        \
        const float4 q6 = P4[f4+6],  q7 = P4[f4+7],  q8  = P4[f4+8];        \
        const float4 q9 = P4[f4+9],  q10 = P4[f4+10], q11 = P4[f4+11];      \
        px0 =q0.x;  py0 =q0.y;  pz0 =q0.z;                                  \
        px1 =q0.w;  py1 =q1.x;  pz1 =q1.y;                                  \
        px2 =q1.z;  py2 =q1.w;  pz2 =q2.x;                                  \
        px3 =q2.y;  py3 =q2.z;  pz3 =q2.w;                                  \
        px4 =q3.x;  py4 =q3.y;  pz4 =q3.z;                                  \
        px5 =q3.w;  py5 =q4.x;  pz5 =q4.y;                                  \
        px6 =q4.z;  py6 =q4.w;  pz6 =q5.x;                                  \
        px7 =q5.y;  py7 =q5.z;  pz7 =q5.w;                                  \
        px8 =q6.x;  py8 =q6.y;  pz8 =q6.z;                                  \
        px9 =q6.w;  py9 =q7.x;  pz9 =q7.y;                                  \
        px10=q7.z;  py10=q7.w;  pz10=q8.x;                                  \
        px11=q8.y;  py11=q8.z;  pz11=q8.w;                                  \
        px12=q9.x;  py12=q9.y;  pz12=q9.z;                                  \
        px13=q9.w;  py13=q10.x; pz13=q10.y;                                 \
        px14=q10.z; py14=q10.w; pz14=q11.x;                                 \
        px15=q11.y; py15=q11.z; pz15=q11.w; }

// ---------------------------------------------------------------------------
// One kernel, three roles, all concurrent (256 blocks x 1024 thr, ~84KB LDS
// -> exactly 1 block/CU on 256 CUs -> guaranteed co-residency for spins).
// __launch_bounds__(1024, 4): LDS already forces 1 block/CU (= 4 waves/EU),
// so declare it -> compiler may allocate up to 128 VGPRs/wave -> the 64-float
// per-thread point state is truly register-resident (no per-iter L2 reload,
// no scratch spills; r11's 3.9MB WRITE_SIZE was spill traffic at 64 VGPRs).
//   bid <  B : FPS for batch bid (r9 bitwise-frozen); RELAXED seed publish.
//              Iter 19's compute skipped (argmax discarded by reference scan;
//              proven r10/r11).
//   bid >= B : kNN radix-select (r9 bitwise-frozen); RELAXED seed poll;
//              threadfence + done-add at end.
//   bid == B : polls done==NKNN*B-1 (init -1), fences, stats in-kernel.
// ---------------------------------------------------------------------------
__global__ __launch_bounds__(1024, 4) void fused_kernel(const float* __restrict__ pcs,
                                                        int* __restrict__ seeds,
                                                        int* __restrict__ done,
                                                        float* __restrict__ topd,
                                                        float* __restrict__ out,
                                                        int B) {
    __shared__ alignas(16) u32 hist[NBIN * NREP];   // 64 KB (knn) / f64 scratch (stats)
    __shared__ u32   part[NBIN];
    __shared__ float cand[CAP];                     // 16 KB (also the >80KB pad)
    __shared__ u32   cnt;
    __shared__ u32   s_thr;
    __shared__ int   s_sid;
    __shared__ u64   s_key[2][16];                  // fps role
    __shared__ float s_cx[2][16], s_cy[2][16], s_cz[2][16];

    const int bid  = blockIdx.x;
    const int t    = threadIdx.x;
    const int lane = t & 63;
    const int wid  = t >> 6;

    if (bid < B) {
        // ================= FPS role (r9 logic, proven absmax 0.0) ==========
        const float* __restrict__ P  = pcs + (size_t)bid * N_PTS * 3;
        const float4* __restrict__ P4 = (const float4*)P;

        FDECL(0)  FDECL(1)  FDECL(2)  FDECL(3)
        FDECL(4)  FDECL(5)  FDECL(6)  FDECL(7)
        FDECL(8)  FDECL(9)  FDECL(10) FDECL(11)
        FDECL(12) FDECL(13) FDECL(14) FDECL(15)
        LOADPTS(P4)

        float cx = P[0], cy = P[1], cz = P[2];
        int farthest = 0;

        for (int it = 0; it < N_SEEDS; ++it) {
            if (t == 0)    // RELAXED: value-only payload (r9-proven)
                __hip_atomic_store(&seeds[bid * N_SEEDS + it], farthest,
                                   __ATOMIC_RELAXED, __HIP_MEMORY_SCOPE_AGENT);
            if (it == N_SEEDS - 1) break;   // last argmax discarded by scan

            float bestv = -1.0f, bx = 0.f, by = 0.f, bz = 0.f;
            int   besti = 0;
#define FSTEP(i) { const float dx = px##i - cx, dy = py##i - cy, dz = pz##i - cz; \
        const float d  = (dx*dx + dy*dy) + dz*dz; \
        const float nd = fminf(dd##i, d); dd##i = nd; \
        if (nd > bestv) { bestv = nd; besti = t*16 + (i); \
                          bx = px##i; by = py##i; bz = pz##i; } }
            FSTEP(0)  FSTEP(1)  FSTEP(2)  FSTEP(3)
            FSTEP(4)  FSTEP(5)  FSTEP(6)  FSTEP(7)
            FSTEP(8)  FSTEP(9)  FSTEP(10) FSTEP(11)
            FSTEP(12) FSTEP(13) FSTEP(14) FSTEP(15)

            float wmax = bestv;
            for (int off = 32; off; off >>= 1)
                wmax = fmaxf(wmax, __shfl_xor(wmax, off));
            const u64 msk = __ballot(bestv == wmax);
            const int low = __ffsll((unsigned long long)msk) - 1;
            const int wi  = __shfl(besti, low);
            const float wx = __shfl(bx, low);
            const float wy = __shfl(by, low);
            const float wz = __shfl(bz, low);

            const int par = it & 1;
            if (lane == 0) {
                s_key[par][wid] = ((u64)__float_as_uint(wmax) << 32) | (u32)(~(u32)wi);
                s_cx[par][wid] = wx; s_cy[par][wid] = wy; s_cz[par][wid] = wz;
            }
            __syncthreads();

            u64 k = s_key[par][lane & 15];
            for (int off = 8; off; off >>= 1) {
                const u64 o = shfl_xor_u64(k, off);
                if (o > k) k = o;
            }
            const int widx = (int)(~(u32)k);
            farthest = widx;
            const int ww = widx >> 10;
            cx = s_cx[par][ww]; cy = s_cy[par][ww]; cz = s_cz[par][ww];
        }
    } else {
        // ================= kNN-select role (r9 bitwise-identical) ==========
        const int kk = bid - B;
        const int b  = kk % B;          // bid ≡ b (mod 8): same XCD as fps block
        const int j  = kk / B;

        const float* __restrict__ P  = pcs + (size_t)b * N_PTS * 3;
        const float4* __restrict__ P4 = (const float4*)P;
        const int rep = t & 31;

        FDECL(0)  FDECL(1)  FDECL(2)  FDECL(3)
        FDECL(4)  FDECL(5)  FDECL(6)  FDECL(7)
        FDECL(8)  FDECL(9)  FDECL(10) FDECL(11)
        FDECL(12) FDECL(13) FDECL(14) FDECL(15)
        LOADPTS(P4)        // dd regs unused -> DCE'd

#pragma unroll
        for (int i = 0; i < (NBIN * NREP) / 1024; ++i) hist[t + i * 1024] = 0u;
        if (t == 0) cnt = 0u;

        for (int s = j; s < N_SEEDS; s += NKNN) {
            if (t == 0) {   // RELAXED poll: seed index is the whole payload
                int sv;
                while ((sv = __hip_atomic_load(&seeds[b * N_SEEDS + s],
                               __ATOMIC_RELAXED, __HIP_MEMORY_SCOPE_AGENT)) < 0)
                    __builtin_amdgcn_s_sleep(2);
                s_sid = sv;
            }
            __syncthreads();                  // B0: sid ready, hist+cnt zeroed
            const int sid = s_sid;
            const float cx = P[sid*3], cy = P[sid*3+1], cz = P[sid*3+2];

            float d0,d1,d2,d3,d4,d5,d6,d7,d8,d9,d10,d11,d12,d13,d14,d15;
#define HSTEP(i) { const float dx = px##i - cx, dy = py##i - cy, dz = pz##i - cz; \
        d##i = fmaf(dz, dz, fmaf(dy, dy, dx * dx)); \
        atomicAdd(&hist[(__float_as_uint(d##i) >> 22) * NREP + rep], 1u); }
            HSTEP(0)  HSTEP(1)  HSTEP(2)  HSTEP(3)
            HSTEP(4)  HSTEP(5)  HSTEP(6)  HSTEP(7)
            HSTEP(8)  HSTEP(9)  HSTEP(10) HSTEP(11)
            HSTEP(12) HSTEP(13) HSTEP(14) HSTEP(15)
            __syncthreads();                  // B1: hist complete

            if (t < NBIN) {
                u32 ssum = 0;
#pragma unroll
                for (int r = 0; r < NREP; ++r)
                    ssum += hist[t * NREP + ((r + t) & (NREP - 1))];
                part[t] = ssum;
            }
            __syncthreads();                  // B2: part[] ready

            if (wid == 0) {
                u32 s8 = 0;
#pragma unroll
                for (int i = 0; i < 8; ++i)
                    s8 += part[lane * 8 + ((i + lane) & 7)];
                u32 cum = s8;
                for (int off = 1; off < 64; off <<= 1) {
                    const u32 o = __shfl_up(cum, off);
                    if (lane >= off) cum += o;
                }
                const u64 mm = __ballot(cum >= (u32)KP1);
                const int L  = __ffsll((unsigned long long)mm) - 1;
                const u32 below = __shfl(cum - s8, L);
                const u32 bc = (lane < 8) ? part[L * 8 + lane] : 0u;
                u32 ic = bc;
                for (int off = 1; off < 8; off <<= 1) {
                    const u32 o = __shfl_up(ic, off);
                    if (lane >= off) ic += o;
                }
                const u64 mm2 = __ballot(lane < 8 && (below + ic) >= (u32)KP1);
                const int l2  = __ffsll((unsigned long long)mm2) - 1;
                if (lane == 0) s_thr = (u32)(L * 8 + l2 + 1) << 22;
            } else {
                if (t == 64) cnt = 0u;        // reset for this seed's collect
                for (int i = t - 64; i < NBIN * NREP; i += 960) hist[i] = 0u;
            }
            __syncthreads();                  // B3: thr ready, hist zeroed, cnt=0

            const float thrf = __uint_as_float(s_thr);
#define CSTEP(i) if (d##i < thrf) { const u32 sl = atomicAdd(&cnt, 1u); \
                                    if (sl < (u32)CAP) cand[sl] = d##i; }
            CSTEP(0)  CSTEP(1)  CSTEP(2)  CSTEP(3)
            CSTEP(4)  CSTEP(5)  CSTEP(6)  CSTEP(7)
            CSTEP(8)  CSTEP(9)  CSTEP(10) CSTEP(11)
            CSTEP(12) CSTEP(13) CSTEP(14) CSTEP(15)
            __syncthreads();                  // B4: candidates ready

            if (wid == 0) {
                const u32 n = min(cnt, (u32)CAP);
                for (u32 base = 0; base < n; base += 64) {
                    const u32 idx = base + (u32)lane;
                    const float vv = (idx < n) ? cand[idx] : 3.0e38f;
                    u32 r = 0;
                    for (u32 jj = 0; jj < n; ++jj) {
                        const float w = cand[jj];
                        r += (w < vv || (w == vv && jj < idx)) ? 1u : 0u;
                    }
                    if (idx < n && r < (u32)KP1)
                        topd[(b * N_SEEDS + s) * KP1 + r] = sqrtf(vv);
                }
            }
        }

        // -------- signal completion (one fence per block, off hot path) ----
        __syncthreads();
        if (t == 0) {
            __threadfence();                  // make topd visible at agent scope
            __hip_atomic_fetch_add(done, 1, __ATOMIC_RELAXED,
                                   __HIP_MEMORY_SCOPE_AGENT);
        }

        // ================= stats role (block B only) =======================
        if (bid == B) {
            const int target = NKNN * B - 1;      // done init = -1 (0xFF memset)
            if (t == 0) {
                while (__hip_atomic_load(done, __ATOMIC_RELAXED,
                                         __HIP_MEMORY_SCOPE_AGENT) != target)
                    __builtin_amdgcn_s_sleep(8);
            }
            __syncthreads();
            __threadfence();    // acquire side: invalidate before topd reads

            const int pairs = B * N_SEEDS;
            const int total = pairs * KP1;
            double* red = (double*)hist;          // 8 KB scratch, hist is dead

            double s1 = 0.0;
            for (int i = t; i < total; i += 1024)
                if (i % KP1 != 0) s1 += (double)topd[i];
            red[t] = s1;
            __syncthreads();
            for (int off = 512; off; off >>= 1) {
                if (t < off) red[t] += red[t + off];
                __syncthreads();
            }
            const double om = red[0] / (double)(pairs * (KP1 - 1));

            double sm = 0.0, sm2 = 0.0;
            for (int pr = t; pr < pairs; pr += 1024) {
                double acc = 0.0;
                for (int jj = 0; jj < KP1; ++jj) acc += (double)topd[pr * KP1 + jj];
                const double m = acc / (om * (double)KP1);
                sm += m;
                sm2 += m * m;
            }
            __syncthreads();
            red[t] = sm;
            __syncthreads();
            for (int off = 512; off; off >>= 1) {
                if (t < off) red[t] += red[t + off];
                __syncthreads();
            }
            const double Sm = red[0];
            __syncthreads();
            red[t] = sm2;
            __syncthreads();
            for (int off = 512; off; off >>= 1) {
                if (t < off) red[t] += red[t + off];
                __syncthreads();
            }
            if (t == 0) {
                const double var = (red[0] - Sm * Sm / (double)pairs)
                                   / (double)(pairs - 1);
                out[0] = (float)var;
            }
        }
    }
}

// ---------------------------------------------------------------------------
extern "C" void kernel_launch(void* const* d_in, const int* in_sizes, int n_in,
                              void* d_out, int out_size, void* d_ws, size_t ws_size,
                              hipStream_t stream) {
    const float* pcs = (const float*)d_in[0];
    const int B = in_sizes[0] / (N_PTS * 3);

    int*   seeds = (int*)d_ws;                          // B*20 ints
    int*   done  = (int*)((char*)d_ws + 5120);          // 1 int, init -1
    float* topd  = (float*)((char*)d_ws + 8192);        // B*20*11 floats
    float* out   = (float*)d_out;

    // seeds -> -1, done -> -1 every launch (graph replays don't re-poison)
    (void)hipMemsetAsync(d_ws, 0xFF, 8192, stream);

    fused_kernel<<<B * (1 + NKNN), 1024, 0, stream>>>(pcs, seeds, done, topd, out, B);
}

// Round 13
// 67.169 us; speedup vs baseline: 1.3863x; 1.0173x over previous
//
#include <hip/hip_runtime.h>

#pragma clang fp contract(off)

#define N_PTS   16384
#define N_SEEDS 20
#define KP1     11      // K+1, K=10
#define NBIN    512     // bits(d2) >> 22 : exponent + 1 mantissa bit
#define NREP    32      // hist[bin*32 + (t&31)] -> bank == t&31 (conflict-free)
#define CAP     4096    // candidate buffer; also LDS pad: >80KB total -> 1 block/CU
#define NKNN    3       // knn-role blocks per batch

typedef unsigned long long u64;
typedef unsigned int       u32;

__device__ __forceinline__ u64 shfl_xor_u64(u64 v, int off) {
    int lo = __shfl_xor((int)(u32)(v & 0xffffffffull), off);
    int hi = __shfl_xor((int)(u32)(v >> 32), off);
    return ((u64)(u32)hi << 32) | (u32)lo;
}

#define FDECL(i) float px##i, py##i, pz##i, dd##i = 1e10f;
#define LOADPTS(P4)                                                         \
    {   const int f4 = t * 12;                                              \
        const float4 q0 = P4[f4+0],  q1 = P4[f4+1],  q2  = P4[f4+2];        \
        const float4 q3 = P4[f4+3],  q4 = P4[f4+4],  q5  = P4[f4+5];        \
        const float4 q6 = P4[f4+6],  q7 = P4[f4+7],  q8  = P4[f4+8];        \
        const float4 q9 = P4[f4+9],  q10 = P4[f4+10], q11 = P4[f4+11];      \
        px0 =q0.x;  py0 =q0.y;  pz0 =q0.z;                                  \
        px1 =q0.w;  py1 =q1.x;  pz1 =q1.y;                                  \
        px2 =q1.z;  py2 =q1.w;  pz2 =q2.x;                                  \
        px3 =q2.y;  py3 =q2.z;  pz3 =q2.w;                                  \
        px4 =q3.x;  py4 =q3.y;  pz4 =q3.z;                                  \
        px5 =q3.w;  py5 =q4.x;  pz5 =q4.y;                                  \
        px6 =q4.z;  py6 =q4.w;  pz6 =q5.x;                                  \
        px7 =q5.y;  py7 =q5.z;  pz7 =q5.w;                                  \
        px8 =q6.x;  py8 =q6.y;  pz8 =q6.z;                                  \
        px9 =q6.w;  py9 =q7.x;  pz9 =q7.y;                                  \
        px10=q7.z;  py10=q7.w;  pz10=q8.x;                                  \
        px11=q8.y;  py11=q8.z;  pz11=q8.w;                                  \
        px12=q9.x;  py12=q9.y;  pz12=q9.z;                                  \
        px13=q9.w;  py13=q10.x; pz13=q10.y;                                 \
        px14=q10.z; py14=q10.w; pz14=q11.x;                                 \
        px15=q11.y; py15=q11.z; pz15=q11.w; }

// ---------------------------------------------------------------------------
// One kernel, three roles, all concurrent (256 blocks x 1024 thr, ~84KB LDS
// -> exactly 1 block/CU on 256 CUs -> guaranteed co-residency for spins).
//   bid <  B : FPS for batch bid; RELAXED seed publish; winner-lane LDS
//              write (no shfl broadcast of idx/coords); iter 19 compute
//              skipped (argmax discarded by reference scan).
//   bid >= B : kNN radix-select (r8-proven body: d recomputed at collect so
//              no 16-reg live range spans the select phase -> lower kernel-
//              wide reg pressure -> no spills in the fps hot loop).
//   bid == B : polls done==NKNN*B-1 (init -1), fences, stats in-kernel.
// ---------------------------------------------------------------------------
__global__ __launch_bounds__(1024, 4) void fused_kernel(const float* __restrict__ pcs,
                                                        int* __restrict__ seeds,
                                                        int* __restrict__ done,
                                                        float* __restrict__ topd,
                                                        float* __restrict__ out,
                                                        int B) {
    __shared__ alignas(16) u32 hist[NBIN * NREP];   // 64 KB (knn) / f64 scratch (stats)
    __shared__ u32   part[NBIN];
    __shared__ float cand[CAP];                     // 16 KB (also the >80KB pad)
    __shared__ u32   cnt;
    __shared__ u32   s_thr;
    __shared__ int   s_sid;
    __shared__ u64   s_key[2][16];                  // fps role
    __shared__ float s_cx[2][16], s_cy[2][16], s_cz[2][16];

    const int bid  = blockIdx.x;
    const int t    = threadIdx.x;
    const int lane = t & 63;
    const int wid  = t >> 6;

    if (bid < B) {
        // ================= FPS role =================
        const float* __restrict__ P  = pcs + (size_t)bid * N_PTS * 3;
        const float4* __restrict__ P4 = (const float4*)P;

        FDECL(0)  FDECL(1)  FDECL(2)  FDECL(3)
        FDECL(4)  FDECL(5)  FDECL(6)  FDECL(7)
        FDECL(8)  FDECL(9)  FDECL(10) FDECL(11)
        FDECL(12) FDECL(13) FDECL(14) FDECL(15)
        LOADPTS(P4)

        float cx = P[0], cy = P[1], cz = P[2];
        int farthest = 0;

        for (int it = 0; it < N_SEEDS; ++it) {
            if (t == 0)    // RELAXED: value-only payload (r9-proven)
                __hip_atomic_store(&seeds[bid * N_SEEDS + it], farthest,
                                   __ATOMIC_RELAXED, __HIP_MEMORY_SCOPE_AGENT);
            if (it == N_SEEDS - 1) break;   // last argmax discarded by scan

            float bestv = -1.0f, bx = 0.f, by = 0.f, bz = 0.f;
            int   besti = 0;
#define FSTEP(i) { const float dx = px##i - cx, dy = py##i - cy, dz = pz##i - cz; \
        const float d  = (dx*dx + dy*dy) + dz*dz; \
        const float nd = fminf(dd##i, d); dd##i = nd; \
        if (nd > bestv) { bestv = nd; besti = t*16 + (i); \
                          bx = px##i; by = py##i; bz = pz##i; } }
            FSTEP(0)  FSTEP(1)  FSTEP(2)  FSTEP(3)
            FSTEP(4)  FSTEP(5)  FSTEP(6)  FSTEP(7)
            FSTEP(8)  FSTEP(9)  FSTEP(10) FSTEP(11)
            FSTEP(12) FSTEP(13) FSTEP(14) FSTEP(15)

            // wave max; the first lane holding it (= lowest index) writes LDS
            float wmax = bestv;
            for (int off = 32; off; off >>= 1)
                wmax = fmaxf(wmax, __shfl_xor(wmax, off));
            const u64 msk = __ballot(bestv == wmax);
            const int low = __ffsll((unsigned long long)msk) - 1;

            const int par = it & 1;
            if (lane == low) {   // winner lane: bestv==wmax, own idx/coords
                s_key[par][wid] = ((u64)__float_as_uint(wmax) << 32) | (u32)(~(u32)besti);
                s_cx[par][wid] = bx; s_cy[par][wid] = by; s_cz[par][wid] = bz;
            }
            __syncthreads();

            u64 k = s_key[par][lane & 15];
            for (int off = 8; off; off >>= 1) {
                const u64 o = shfl_xor_u64(k, off);
                if (o > k) k = o;
            }
            const int widx = (int)(~(u32)k);
            farthest = widx;
            const int ww = widx >> 10;
            cx = s_cx[par][ww]; cy = s_cy[par][ww]; cz = s_cz[par][ww];
        }
    } else {
        // ================= kNN-select role (r8-proven body) ================
        const int kk = bid - B;
        const int b  = kk % B;          // bid ≡ b (mod 8): same XCD as fps block
        const int j  = kk / B;

        const float* __restrict__ P  = pcs + (size_t)b * N_PTS * 3;
        const float4* __restrict__ P4 = (const float4*)P;
        const int rep = t & 31;

        FDECL(0)  FDECL(1)  FDECL(2)  FDECL(3)
        FDECL(4)  FDECL(5)  FDECL(6)  FDECL(7)
        FDECL(8)  FDECL(9)  FDECL(10) FDECL(11)
        FDECL(12) FDECL(13) FDECL(14) FDECL(15)
        LOADPTS(P4)        // dd regs unused -> DCE'd

#pragma unroll
        for (int i = 0; i < (NBIN * NREP) / 1024; ++i) hist[t + i * 1024] = 0u;
        if (t == 0) cnt = 0u;

        for (int s = j; s < N_SEEDS; s += NKNN) {
            if (t == 0) {   // RELAXED poll: seed index is the whole payload
                int sv;
                while ((sv = __hip_atomic_load(&seeds[b * N_SEEDS + s],
                               __ATOMIC_RELAXED, __HIP_MEMORY_SCOPE_AGENT)) < 0)
                    __builtin_amdgcn_s_sleep(2);
                s_sid = sv;
            }
            __syncthreads();                  // B0: sid ready, hist+cnt zeroed
            const int sid = s_sid;
            const float cx = P[sid*3], cy = P[sid*3+1], cz = P[sid*3+2];

            // ---- histogram pass (d transient: NO 16-reg live range) -------
#define HSTEP(i) { const float dx = px##i - cx, dy = py##i - cy, dz = pz##i - cz; \
        const float d = fmaf(dz, dz, fmaf(dy, dy, dx * dx)); \
        atomicAdd(&hist[(__float_as_uint(d) >> 22) * NREP + rep], 1u); }
            HSTEP(0)  HSTEP(1)  HSTEP(2)  HSTEP(3)
            HSTEP(4)  HSTEP(5)  HSTEP(6)  HSTEP(7)
            HSTEP(8)  HSTEP(9)  HSTEP(10) HSTEP(11)
            HSTEP(12) HSTEP(13) HSTEP(14) HSTEP(15)
            __syncthreads();                  // B1: hist complete

            if (t < NBIN) {
                u32 ssum = 0;
#pragma unroll
                for (int r = 0; r < NREP; ++r)
                    ssum += hist[t * NREP + ((r + t) & (NREP - 1))];
                part[t] = ssum;
            }
            __syncthreads();                  // B2: part[] ready

            if (wid == 0) {
                u32 s8 = 0;
#pragma unroll
                for (int i = 0; i < 8; ++i)
                    s8 += part[lane * 8 + ((i + lane) & 7)];
                u32 cum = s8;
                for (int off = 1; off < 64; off <<= 1) {
                    const u32 o = __shfl_up(cum, off);
                    if (lane >= off) cum += o;
                }
                const u64 mm = __ballot(cum >= (u32)KP1);
                const int L  = __ffsll((unsigned long long)mm) - 1;
                const u32 below = __shfl(cum - s8, L);
                const u32 bc = (lane < 8) ? part[L * 8 + lane] : 0u;
                u32 ic = bc;
                for (int off = 1; off < 8; off <<= 1) {
                    const u32 o = __shfl_up(ic, off);
                    if (lane >= off) ic += o;
                }
                const u64 mm2 = __ballot(lane < 8 && (below + ic) >= (u32)KP1);
                const int l2  = __ffsll((unsigned long long)mm2) - 1;
                if (lane == 0) s_thr = (u32)(L * 8 + l2 + 1) << 22;
            } else {
                if (t == 64) cnt = 0u;        // reset for this seed's collect
                for (int i = t - 64; i < NBIN * NREP; i += 960) hist[i] = 0u;
            }
            __syncthreads();                  // B3: thr ready, hist zeroed, cnt=0

            // ---- collect candidates (recompute d: bitwise same as HSTEP) --
            const float thrf = __uint_as_float(s_thr);
#define CSTEP(i) { const float dx = px##i - cx, dy = py##i - cy, dz = pz##i - cz; \
        const float d = fmaf(dz, dz, fmaf(dy, dy, dx * dx)); \
        if (d < thrf) { const u32 sl = atomicAdd(&cnt, 1u); \
                        if (sl < (u32)CAP) cand[sl] = d; } }
            CSTEP(0)  CSTEP(1)  CSTEP(2)  CSTEP(3)
            CSTEP(4)  CSTEP(5)  CSTEP(6)  CSTEP(7)
            CSTEP(8)  CSTEP(9)  CSTEP(10) CSTEP(11)
            CSTEP(12) CSTEP(13) CSTEP(14) CSTEP(15)
            __syncthreads();                  // B4: candidates ready

            if (wid == 0) {
                const u32 n = min(cnt, (u32)CAP);
                for (u32 base = 0; base < n; base += 64) {
                    const u32 idx = base + (u32)lane;
                    const float vv = (idx < n) ? cand[idx] : 3.0e38f;
                    u32 r = 0;
                    for (u32 jj = 0; jj < n; ++jj) {
                        const float w = cand[jj];
                        r += (w < vv || (w == vv && jj < idx)) ? 1u : 0u;
                    }
                    if (idx < n && r < (u32)KP1)
                        topd[(b * N_SEEDS + s) * KP1 + r] = sqrtf(vv);
                }
            }
        }

        // -------- signal completion (one fence per block, off hot path) ----
        __syncthreads();
        if (t == 0) {
            __threadfence();                  // make topd visible at agent scope
            __hip_atomic_fetch_add(done, 1, __ATOMIC_RELAXED,
                                   __HIP_MEMORY_SCOPE_AGENT);
        }

        // ================= stats role (block B only) =======================
        if (bid == B) {
            const int target = NKNN * B - 1;      // done init = -1 (0xFF memset)
            if (t == 0) {
                while (__hip_atomic_load(done, __ATOMIC_RELAXED,
                                         __HIP_MEMORY_SCOPE_AGENT) != target)
                    __builtin_amdgcn_s_sleep(8);
            }
            __syncthreads();
            __threadfence();    // acquire side: invalidate before topd reads

            const int pairs = B * N_SEEDS;
            const int total = pairs * KP1;
            double* red = (double*)hist;          // 8 KB scratch, hist is dead

            double s1 = 0.0;
            for (int i = t; i < total; i += 1024)
                if (i % KP1 != 0) s1 += (double)topd[i];
            red[t] = s1;
            __syncthreads();
            for (int off = 512; off; off >>= 1) {
                if (t < off) red[t] += red[t + off];
                __syncthreads();
            }
            const double om = red[0] / (double)(pairs * (KP1 - 1));

            double sm = 0.0, sm2 = 0.0;
            for (int pr = t; pr < pairs; pr += 1024) {
                double acc = 0.0;
                for (int jj = 0; jj < KP1; ++jj) acc += (double)topd[pr * KP1 + jj];
                const double m = acc / (om * (double)KP1);
                sm += m;
                sm2 += m * m;
            }
            __syncthreads();
            red[t] = sm;
            __syncthreads();
            for (int off = 512; off; off >>= 1) {
                if (t < off) red[t] += red[t + off];
                __syncthreads();
            }
            const double Sm = red[0];
            __syncthreads();
            red[t] = sm2;
            __syncthreads();
            for (int off = 512; off; off >>= 1) {
                if (t < off) red[t] += red[t + off];
                __syncthreads();
            }
            if (t == 0) {
                const double var = (red[0] - Sm * Sm / (double)pairs)
                                   / (double)(pairs - 1);
                out[0] = (float)var;
            }
        }
    }
}

// ---------------------------------------------------------------------------
extern "C" void kernel_launch(void* const* d_in, const int* in_sizes, int n_in,
                              void* d_out, int out_size, void* d_ws, size_t ws_size,
                              hipStream_t stream) {
    const float* pcs = (const float*)d_in[0];
    const int B = in_sizes[0] / (N_PTS * 3);

    int*   seeds = (int*)d_ws;                          // B*20 ints
    int*   done  = (int*)((char*)d_ws + 5120);          // 1 int, init -1
    float* topd  = (float*)((char*)d_ws + 8192);        // B*20*11 floats
    float* out   = (float*)d_out;

    // seeds -> -1, done -> -1 every launch (graph replays don't re-poison)
    (void)hipMemsetAsync(d_ws, 0xFF, 8192, stream);

    fused_kernel<<<B * (1 + NKNN), 1024, 0, stream>>>(pcs, seeds, done, topd, out, B);
}